// Round 4
// baseline (145.799 us; speedup 1.0000x reference)
//
#include <hip/hip_runtime.h>
#include <hip/hip_bf16.h>
#include <math.h>

// ---- problem constants ----
#define BATCH 16
#define CIN   128
#define COUT  128
#define SS    3136          // 56*56
#define XT_ROW 8192         // shorts per padded row: 64 pcol * 128 ci
#define XT_PER_B (58*XT_ROW)
#define NKB   18

typedef __attribute__((ext_vector_type(8))) __bf16 bf16x8;
typedef __attribute__((ext_vector_type(4))) float  floatx4;

static __device__ __forceinline__ unsigned short f2bf(float f) {
  union { float f; unsigned u; } v; v.f = f;
  unsigned r = v.u + 0x7fffu + ((v.u >> 16) & 1u);   // RNE
  return (unsigned short)(r >> 16);
}
static __device__ __forceinline__ float bf2f(unsigned short u) {
  union { unsigned u; float f; } v; v.u = ((unsigned)u) << 16; return v.f;
}

static __device__ __forceinline__ float waveReduceSum(float v) {
  #pragma unroll
  for (int off = 32; off > 0; off >>= 1) v += __shfl_xor(v, off, 64);
  return v;
}

static __device__ __forceinline__ void load_lds16(const void* g, void* l) {
  __builtin_amdgcn_global_load_lds(
      (const __attribute__((address_space(1))) void*)g,
      (__attribute__((address_space(3))) void*)l, 16, 0, 0);
}

#define ASM_WAIT_VM4   asm volatile("s_waitcnt vmcnt(4)" ::: "memory")
#define ASM_WAIT_VM0   asm volatile("s_waitcnt vmcnt(0)" ::: "memory")
#define ASM_WAIT_LGKM0 asm volatile("s_waitcnt lgkmcnt(0)" ::: "memory")
#define BARRIER        __builtin_amdgcn_s_barrier()

// K0: fused pad+transpose to NHWC bf16 + attention exp(mask) + zsum accumulation.
// grid (58, 16), block 256. xT[b][prow][pcol][ci]; att[b][s] = exp(mask) (no max
// subtraction: mask values are O(1), softmax is shift-invariant).
__global__ void k0_padT(const float* __restrict__ x, const float* __restrict__ w_mask,
                        const float* __restrict__ b_mask,
                        unsigned short* __restrict__ xT, float* __restrict__ att,
                        float* __restrict__ zsum) {
  int b = blockIdx.y, prow = blockIdx.x, t = threadIdx.x;
  int y = prow - 1;
  __shared__ unsigned short sx[128 * 58];   // row stride 58 (odd word-stride -> spread banks)
  __shared__ float swm[128];
  __shared__ float red[4 * 56];
  bool rowvalid = ((unsigned)y < 56u);
  if (t < 128) swm[t] = w_mask[t];
  if (rowvalid) {
    int ci = t >> 1, h = t & 1;
    const float* src = x + (size_t)(b * 128 + ci) * SS + y * 56 + h * 28;
    #pragma unroll
    for (int c = 0; c < 28; c++) sx[ci * 58 + h * 28 + c] = f2bf(src[c]);
  } else {
    for (int i = t; i < 128 * 58; i += 256) sx[i] = 0;
  }
  __syncthreads();
  if (rowvalid && t < 224) {
    int xx = t % 56, g = t / 56;
    float acc = 0.f;
    #pragma unroll
    for (int k = 0; k < 32; k++) {
      int ci = g * 32 + k;
      acc += bf2f(sx[ci * 58 + xx]) * swm[ci];
    }
    red[g * 56 + xx] = acc;
  }
  __syncthreads();
  float e = 0.f;
  if (rowvalid && t < 56) {
    float m = red[t] + red[56 + t] + red[112 + t] + red[168 + t] + b_mask[0];
    e = expf(m);
    att[b * SS + y * 56 + t] = e;
  }
  if (t < 64) {
    float s = waveReduceSum(e);
    if (t == 0 && rowvalid) atomicAdd(zsum + b, s);
  }
  // NHWC write: thread t -> pcol = t>>2, ci block = (t&3)*32, 64B contiguous
  int pcol = t >> 2, cig = t & 3;
  int xx = pcol - 1;
  bool colv = rowvalid && ((unsigned)xx < 56u);
  unsigned short tmp[32];
  #pragma unroll
  for (int i = 0; i < 32; i++)
    tmp[i] = colv ? sx[(cig * 32 + i) * 58 + xx] : (unsigned short)0;
  unsigned short* dst = xT + ((size_t)(b * 58 + prow) * 64 + pcol) * 128 + cig * 32;
  #pragma unroll
  for (int q = 0; q < 4; q++)
    *reinterpret_cast<uint4*>(dst + q * 8) = *reinterpret_cast<const uint4*>(tmp + q * 8);
}

// K3: ctx[b,c] = (1/zsum[b]) * sum_s x[b,c,s]*att[b,s]   (att already = exp)
__global__ void k3_ctx(const float* __restrict__ x, const float* __restrict__ att,
                       const float* __restrict__ zsum, float* __restrict__ ctx) {
  int c = blockIdx.x, b = blockIdx.y, t = threadIdx.x;
  const float4* xb = (const float4*)(x + ((size_t)b * CIN + c) * SS);
  const float4* ab = (const float4*)(att + b * SS);
  float acc = 0.f;
  for (int i = t; i < 784; i += 256) {
    float4 xv = xb[i], av = ab[i];
    acc += xv.x * av.x + xv.y * av.y + xv.z * av.z + xv.w * av.w;
  }
  __shared__ float red[4];
  acc = waveReduceSum(acc);
  if ((t & 63) == 0) red[t >> 6] = acc;
  __syncthreads();
  if (t == 0) ctx[b * CIN + c] = (red[0] + red[1] + red[2] + red[3]) / zsum[b];
}

// K4: bottleneck MLP
__global__ void k4_transform(const float* __restrict__ ctx, const float* __restrict__ w1,
                             const float* __restrict__ b1, const float* __restrict__ ln_g,
                             const float* __restrict__ ln_b, const float* __restrict__ w2,
                             const float* __restrict__ b2, float* __restrict__ aout) {
  int b = blockIdx.x, t = threadIdx.x;   // 64 threads
  __shared__ float sc[128], st[16], sn[16];
  sc[t] = ctx[b * 128 + t];
  sc[t + 64] = ctx[b * 128 + t + 64];
  __syncthreads();
  if (t < 16) {
    float acc = b1[t];
    #pragma unroll 8
    for (int c = 0; c < 128; c++) acc += sc[c] * w1[t * 128 + c];
    st[t] = acc;
  }
  __syncthreads();
  float mu = 0.f, m2 = 0.f;
  #pragma unroll
  for (int r = 0; r < 16; r++) { mu += st[r]; m2 += st[r] * st[r]; }
  mu *= (1.f / 16.f); m2 *= (1.f / 16.f);
  float rstd = rsqrtf(m2 - mu * mu + 1e-5f);
  if (t < 16) {
    float v = (st[t] - mu) * rstd * ln_g[t] + ln_b[t];
    sn[t] = fmaxf(v, 0.f);
  }
  __syncthreads();
  #pragma unroll
  for (int i = 0; i < 4; i++) {
    int mo = t + 64 * i;
    float acc = b2[mo];
    #pragma unroll
    for (int r = 0; r < 16; r++) acc += sn[r] * w2[mo * 16 + r];
    aout[b * 256 + mo] = 1.f / (1.f + expf(-acc));
  }
}

// K5: wd[b][co][kb][kq(swizzled)] ; K-order within step kb: ci=(kb&1)*64+kq, khw=kb>>1.
__global__ void k5_wdgen(const float* __restrict__ a, const float* __restrict__ w_fc,
                         const float* __restrict__ b_fc, unsigned short* __restrict__ wd) {
  int co = blockIdx.x, b = blockIdx.y, t = threadIdx.x;   // 128 threads
  float a0 = a[b * 256 + 2 * co], a1 = a[b * 256 + 2 * co + 1];
  const float* wrow = w_fc + co * 1152;
  const float* brow = b_fc + co * 1152;
  unsigned short* drow = wd + (size_t)(b * 128 + co) * 1152;
  #pragma unroll
  for (int r = 0; r < 9; r++) {
    int e = t + 128 * r;
    int ci = e / 9, khw = e - (e / 9) * 9;
    float v = (ci < 64 ? a0 : a1) * wrow[e] + brow[e];
    int kb = khw * 2 + (ci >> 6);
    int kq = ci & 63;
    int pos = (((kq >> 3) ^ (co & 7)) << 3) | (kq & 7);
    drow[kb * 64 + pos] = f2bf(v);
  }
}

// K6: implicit-GEMM conv, 512 threads, tile 128co x 128s, DOUBLE-BUFFERED LDS,
// raw s_barrier + fine-grained vmcnt waits: step kb+1's DMA stays in flight
// during compute on step kb (no vmcnt(0) drain mid-loop).
__global__ __launch_bounds__(512, 4) void k6_conv(const unsigned short* __restrict__ xT,
                                                  const unsigned short* __restrict__ wd,
                                                  float* __restrict__ out) {
  __shared__ __align__(16) unsigned short As[2][8192];   // [buf][co128][kq64]
  __shared__ __align__(16) unsigned short Bs[2][8192];   // [buf][s128][kq64]
  int t = threadIdx.x;
  int b = blockIdx.y, y0 = blockIdx.x * 2;
  int wave = t >> 6, lane = t & 63, l15 = lane & 15, quad = lane >> 4;
  int x7 = lane & 7;
  const unsigned short* wp  = wd + (size_t)b * (128 * 1152);
  const unsigned short* xTb = xT + (size_t)b * XT_PER_B;

  // DMA chunk ids (16B units): this thread covers ch0, ch1 of 1024
  int ch0 = wave * 128 + lane, ch1 = ch0 + 64;
  int offA0 = (ch0 >> 3) * 1152 + (ch0 & 7) * 8;      // + kb*64 per step
  int offA1 = (ch1 >> 3) * 1152 + (ch1 & 7) * 8;
  int s0 = ch0 >> 3, s1 = ch1 >> 3;
  int c_ = lane & 7;
  int sr0 = s0 / 56, sc0 = s0 - sr0 * 56; if (sr0 >= 2) { sr0 = 0; sc0 = 0; }
  int sr1 = s1 / 56, sc1 = s1 - sr1 * 56; if (sr1 >= 2) { sr1 = 0; sc1 = 0; }
  int offB0 = (y0 + sr0) * XT_ROW + sc0 * 128 + (c_ ^ (s0 & 7)) * 8;
  int offB1 = (y0 + sr1) * XT_ROW + sc1 * 128 + (c_ ^ (s1 & 7)) * 8;

  int s_base = (wave & 3) * 32;
  int co_b   = (wave >> 2) * 64;

  floatx4 acc[4][2];
  floatx4 zero = {0.f, 0.f, 0.f, 0.f};
  #pragma unroll
  for (int i = 0; i < 4; i++)
    #pragma unroll
    for (int j = 0; j < 2; j++) acc[i][j] = zero;

#define ISSUE(KB, P) do {                                             \
    int khw_ = (KB) >> 1; int kh_ = khw_ / 3;                          \
    int kw_ = khw_ - kh_ * 3;                                          \
    int dB_ = kh_ * XT_ROW + kw_ * 128 + (((KB) & 1) << 6);            \
    int dA_ = (KB) * 64;                                               \
    load_lds16(wp + offA0 + dA_, &As[P][wave * 1024]);                 \
    load_lds16(wp + offA1 + dA_, &As[P][wave * 1024 + 512]);           \
    load_lds16(xTb + offB0 + dB_, &Bs[P][wave * 1024]);                \
    load_lds16(xTb + offB1 + dB_, &Bs[P][wave * 1024 + 512]);          \
  } while (0)

#define COMPUTE(P) do {                                                           \
    _Pragma("unroll")                                                             \
    for (int kk = 0; kk < 2; kk++) {                                              \
      bf16x8 af[4], bfr[2];                                                       \
      int pc = ((kk * 4 + quad) ^ x7) << 3;                                       \
      _Pragma("unroll")                                                           \
      for (int i = 0; i < 4; i++)                                                 \
        af[i] = *reinterpret_cast<const bf16x8*>(&As[P][(co_b + i * 16 + l15) * 64 + pc]); \
      _Pragma("unroll")                                                           \
      for (int j = 0; j < 2; j++)                                                 \
        bfr[j] = *reinterpret_cast<const bf16x8*>(&Bs[P][(s_base + j * 16 + l15) * 64 + pc]); \
      _Pragma("unroll")                                                           \
      for (int i = 0; i < 4; i++)                                                 \
        _Pragma("unroll")                                                         \
        for (int j = 0; j < 2; j++)                                               \
          acc[i][j] = __builtin_amdgcn_mfma_f32_16x16x32_bf16(af[i], bfr[j], acc[i][j], 0, 0, 0); \
    }                                                                             \
  } while (0)

  ISSUE(0, 0);
  ISSUE(1, 1);
  #pragma unroll 1
  for (int kb = 0; kb < 16; kb += 2) {
    ASM_WAIT_VM4;   // own step-kb DMAs done (step kb+1's 4 stay in flight)
    BARRIER;        // all waves' step-kb DMAs done
    COMPUTE(0);
    ASM_WAIT_LGKM0;
    BARRIER;        // all waves finished reading buf0
    ISSUE(kb + 2, 0);
    ASM_WAIT_VM4;
    BARRIER;
    COMPUTE(1);
    ASM_WAIT_LGKM0;
    BARRIER;
    ISSUE(kb + 3, 1);
  }
  // kb = 16 (buf0), kb = 17 (buf1); nothing left to prefetch
  ASM_WAIT_VM4;
  BARRIER;
  COMPUTE(0);
  ASM_WAIT_VM0;
  BARRIER;
  COMPUTE(1);
#undef ISSUE
#undef COMPUTE

  // epilogue: D col (l15) -> s, row (quad*4+r) -> co
  float* ob = out + (size_t)b * COUT * SS + y0 * 56;
  #pragma unroll
  for (int i = 0; i < 4; i++) {
    #pragma unroll
    for (int j = 0; j < 2; j++) {
      int sl = s_base + j * 16 + l15;
      if (sl < 112) {
        int row = (sl >= 56) ? 1 : 0;
        int col = sl - row * 56;
        #pragma unroll
        for (int r = 0; r < 4; r++) {
          int co = co_b + i * 16 + quad * 4 + r;
          ob[(size_t)co * SS + row * 56 + col] = acc[i][j][r];
        }
      }
    }
  }
}

extern "C" void kernel_launch(void* const* d_in, const int* in_sizes, int n_in,
                              void* d_out, int out_size, void* d_ws, size_t ws_size,
                              hipStream_t stream) {
  const float* x      = (const float*)d_in[0];
  const float* w_mask = (const float*)d_in[1];
  const float* b_mask = (const float*)d_in[2];
  const float* w1     = (const float*)d_in[3];
  const float* b1     = (const float*)d_in[4];
  const float* ln_g   = (const float*)d_in[5];
  const float* ln_b   = (const float*)d_in[6];
  const float* w2     = (const float*)d_in[7];
  const float* b2     = (const float*)d_in[8];
  const float* w_fc   = (const float*)d_in[9];
  const float* b_fc   = (const float*)d_in[10];
  float* out = (float*)d_out;

  char* ws = (char*)d_ws;
  unsigned short* xT  = (unsigned short*)(ws);               // 15,204,352 B
  unsigned short* wdw = (unsigned short*)(ws + 15204352);    //  4,718,592 B
  float* att  = (float*)(ws + 19922944);                     //    200,704 B
  float* ctx  = (float*)(ws + 20123648);                     //      8,192 B
  float* aact = (float*)(ws + 20131840);                     //     16,384 B
  float* zsum = (float*)(ws + 20148224);                     //         64 B

  hipMemsetAsync(zsum, 0, 64, stream);
  k0_padT     <<<dim3(58, 16),   dim3(256),  0, stream>>>(x, w_mask, b_mask, xT, att, zsum);
  k3_ctx      <<<dim3(128, 16),  dim3(256),  0, stream>>>(x, att, zsum, ctx);
  k4_transform<<<dim3(16),       dim3(64),   0, stream>>>(ctx, w1, b1, ln_g, ln_b, w2, b2, aact);
  k5_wdgen    <<<dim3(128, 16),  dim3(128),  0, stream>>>(aact, w_fc, b_fc, wdw);
  k6_conv     <<<dim3(28, 16),   dim3(512),  0, stream>>>(xT, wdw, out);
}

// Round 5
// 133.951 us; speedup vs baseline: 1.0885x; 1.0885x over previous
//
#include <hip/hip_runtime.h>
#include <hip/hip_bf16.h>
#include <math.h>

// ---- problem constants ----
#define BATCH 16
#define CIN   128
#define COUT  128
#define SS    3136          // 56*56
#define XT_ROW 8192         // shorts per padded row: 64 pcol * 128 ci
#define XT_PER_B (58*XT_ROW)
#define NKB   18

typedef __attribute__((ext_vector_type(8))) __bf16 bf16x8;
typedef __attribute__((ext_vector_type(4))) float  floatx4;

static __device__ __forceinline__ unsigned short f2bf(float f) {
  union { float f; unsigned u; } v; v.f = f;
  unsigned r = v.u + 0x7fffu + ((v.u >> 16) & 1u);   // RNE
  return (unsigned short)(r >> 16);
}
static __device__ __forceinline__ float bf2f(unsigned short u) {
  union { unsigned u; float f; } v; v.u = ((unsigned)u) << 16; return v.f;
}

static __device__ __forceinline__ float waveReduceSum(float v) {
  #pragma unroll
  for (int off = 32; off > 0; off >>= 1) v += __shfl_xor(v, off, 64);
  return v;
}

static __device__ __forceinline__ void load_lds16(const void* g, void* l) {
  __builtin_amdgcn_global_load_lds(
      (const __attribute__((address_space(1))) void*)g,
      (__attribute__((address_space(3))) void*)l, 16, 0, 0);
}

// K0: fused pad+transpose to NHWC bf16 + attention mask row + exp + per-row
// context partials. No softmax max-subtraction (mask is O(1), shift-invariant).
// Outputs: xT[b][prow][pcol][ci], rowsum[b][prow] = sum_x exp(mask),
//          pctx[b][prow][c] = sum_x x_bf16[c,x]*exp(mask[x])   (zeros on pad rows)
__global__ void k0_padT(const float* __restrict__ x, const float* __restrict__ w_mask,
                        const float* __restrict__ b_mask,
                        unsigned short* __restrict__ xT, float* __restrict__ rowsum,
                        float* __restrict__ pctx) {
  int b = blockIdx.y, prow = blockIdx.x, t = threadIdx.x;
  int y = prow - 1;
  __shared__ unsigned short sx[128 * 58];   // row stride 58 (odd word-stride -> spread banks)
  __shared__ float swm[128];
  __shared__ float red[4 * 56];
  __shared__ float se[56];
  bool rowvalid = ((unsigned)y < 56u);
  if (t < 128) swm[t] = w_mask[t];
  if (rowvalid) {
    int ci = t >> 1, h = t & 1;
    const float* src = x + (size_t)(b * 128 + ci) * SS + y * 56 + h * 28;
    #pragma unroll
    for (int c = 0; c < 28; c++) sx[ci * 58 + h * 28 + c] = f2bf(src[c]);
  } else {
    for (int i = t; i < 128 * 58; i += 256) sx[i] = 0;
  }
  __syncthreads();
  if (rowvalid && t < 224) {
    int xx = t % 56, g = t / 56;
    float acc = 0.f;
    #pragma unroll
    for (int k = 0; k < 32; k++) {
      int ci = g * 32 + k;
      acc += bf2f(sx[ci * 58 + xx]) * swm[ci];
    }
    red[g * 56 + xx] = acc;
  }
  __syncthreads();
  float e = 0.f;
  if (rowvalid && t < 56) {
    float m = red[t] + red[56 + t] + red[112 + t] + red[168 + t] + b_mask[0];
    e = expf(m);
    se[t] = e;
  }
  if (t < 64) {
    float s = waveReduceSum(e);
    if (t == 0) rowsum[b * 58 + prow] = s;   // 0 on pad rows
  }
  __syncthreads();   // se ready
  // context partials: thread (c = t>>1, h = t&1) does 28 MACs, pair-combine
  {
    int c = t >> 1, h = t & 1;
    float acc = 0.f;
    if (rowvalid) {
      #pragma unroll
      for (int j = 0; j < 28; j++)
        acc += bf2f(sx[c * 58 + h * 28 + j]) * se[h * 28 + j];
    }
    acc += __shfl_xor(acc, 1, 64);
    if (h == 0) pctx[(size_t)(b * 58 + prow) * 128 + c] = acc;  // 0 on pad rows
  }
  // NHWC write: thread t -> pcol = t>>2, ci block = (t&3)*32, 64B contiguous
  int pcol = t >> 2, cig = t & 3;
  int xx = pcol - 1;
  bool colv = rowvalid && ((unsigned)xx < 56u);
  unsigned short tmp[32];
  #pragma unroll
  for (int i = 0; i < 32; i++)
    tmp[i] = colv ? sx[(cig * 32 + i) * 58 + xx] : (unsigned short)0;
  unsigned short* dst = xT + ((size_t)(b * 58 + prow) * 64 + pcol) * 128 + cig * 32;
  #pragma unroll
  for (int q = 0; q < 4; q++)
    *reinterpret_cast<uint4*>(dst + q * 8) = *reinterpret_cast<const uint4*>(tmp + q * 8);
}

// K5: fused ctx-reduction + bottleneck MLP + per-sample weight generation.
// grid (co=128, b=16), 128 threads. wd[b][co][kb][kq(swizzled)].
__global__ void k5_gen(const float* __restrict__ rowsum, const float* __restrict__ pctx,
                       const float* __restrict__ w1, const float* __restrict__ b1,
                       const float* __restrict__ ln_g, const float* __restrict__ ln_b,
                       const float* __restrict__ w2, const float* __restrict__ b2,
                       const float* __restrict__ w_fc, const float* __restrict__ b_fc,
                       unsigned short* __restrict__ wd) {
  int co = blockIdx.x, b = blockIdx.y, t = threadIdx.x;
  __shared__ float sc[128], st[16], sn[16], sa[2], shz;
  // zsum (wave 0) + ctx reduction (all threads)
  float rv = (t < 58) ? rowsum[b * 58 + t] : 0.f;
  float acc = 0.f;
  #pragma unroll
  for (int r = 0; r < 58; r++) acc += pctx[(size_t)(b * 58 + r) * 128 + t];
  if (t < 64) {
    float z = waveReduceSum(rv);
    if (t == 0) shz = 1.0f / z;
  }
  __syncthreads();
  sc[t] = acc * shz;
  __syncthreads();
  // MLP stage 1: t = ctx @ w1^T + b1   (16 threads, 128 MACs each)
  if (t < 16) {
    float s = b1[t];
    #pragma unroll 8
    for (int c = 0; c < 128; c++) s += sc[c] * w1[t * 128 + c];
    st[t] = s;
  }
  __syncthreads();
  // LayerNorm (redundant across threads) + ReLU
  float mu = 0.f, m2 = 0.f;
  #pragma unroll
  for (int r = 0; r < 16; r++) { float v = st[r]; mu += v; m2 += v * v; }
  mu *= (1.f / 16.f); m2 *= (1.f / 16.f);
  float rstd = rsqrtf(m2 - mu * mu + 1e-5f);
  if (t < 16) {
    float v = (st[t] - mu) * rstd * ln_g[t] + ln_b[t];
    sn[t] = fmaxf(v, 0.f);
  }
  __syncthreads();
  // MLP stage 2: only rows 2co, 2co+1 of w2 needed
  if (t < 2) {
    int mo = 2 * co + t;
    float s = b2[mo];
    #pragma unroll
    for (int r = 0; r < 16; r++) s += sn[r] * w2[mo * 16 + r];
    sa[t] = 1.f / (1.f + expf(-s));
  }
  __syncthreads();
  float a0 = sa[0], a1 = sa[1];
  // weight generation (coalesced w_fc/b_fc reads, swizzled panel writes)
  const float* wrow = w_fc + co * 1152;
  const float* brow = b_fc + co * 1152;
  unsigned short* drow = wd + (size_t)(b * 128 + co) * 1152;
  #pragma unroll
  for (int r = 0; r < 9; r++) {
    int e = t + 128 * r;
    int ci = e / 9, khw = e - (e / 9) * 9;
    float v = (ci < 64 ? a0 : a1) * wrow[e] + brow[e];
    int kb = khw * 2 + (ci >> 6);
    int kq = ci & 63;
    int pos = (((kq >> 3) ^ (co & 7)) << 3) | (kq & 7);
    drow[kb * 64 + pos] = f2bf(v);
  }
}

// K6: implicit-GEMM conv, 512 threads, tile 128co x 128s (2 out rows),
// both operands staged via global_load_lds (A: pre-swizzled weight rows,
// B: NHWC rows with source-permuted XOR swizzle). acc[4][2] per wave.
// (round-3 structure — explicit double-buffer variant regressed, reverted)
__global__ __launch_bounds__(512, 4) void k6_conv(const unsigned short* __restrict__ xT,
                                                  const unsigned short* __restrict__ wd,
                                                  float* __restrict__ out) {
  __shared__ __align__(16) unsigned short As[8192];   // [co128][kq64]
  __shared__ __align__(16) unsigned short Bs[8192];   // [s128][kq64]
  int t = threadIdx.x;
  int b = blockIdx.y, y0 = blockIdx.x * 2;
  int wave = t >> 6, lane = t & 63, l15 = lane & 15, quad = lane >> 4;
  int x7 = lane & 7;
  const unsigned short* wp  = wd + (size_t)b * (128 * 1152);
  const unsigned short* xTb = xT + (size_t)b * XT_PER_B;

  // DMA chunk ids (16B units): this thread covers ch0, ch1 of 1024
  int ch0 = wave * 128 + lane, ch1 = ch0 + 64;
  int offA0 = (ch0 >> 3) * 1152 + (ch0 & 7) * 8;      // + kb*64 per step
  int offA1 = (ch1 >> 3) * 1152 + (ch1 & 7) * 8;
  int s0 = ch0 >> 3, s1 = ch1 >> 3;
  int c_ = lane & 7;
  int sr0 = s0 / 56, sc0 = s0 - sr0 * 56; if (sr0 >= 2) { sr0 = 0; sc0 = 0; }
  int sr1 = s1 / 56, sc1 = s1 - sr1 * 56; if (sr1 >= 2) { sr1 = 0; sc1 = 0; }
  int offB0 = (y0 + sr0) * XT_ROW + sc0 * 128 + (c_ ^ (s0 & 7)) * 8;
  int offB1 = (y0 + sr1) * XT_ROW + sc1 * 128 + (c_ ^ (s1 & 7)) * 8;
  unsigned short* dA0 = &As[wave * 1024];
  unsigned short* dA1 = &As[wave * 1024 + 512];
  unsigned short* dB0 = &Bs[wave * 1024];
  unsigned short* dB1 = &Bs[wave * 1024 + 512];

  int s_base = (wave & 3) * 32;
  int co_b   = (wave >> 2) * 64;

  floatx4 acc[4][2];
  floatx4 zero = {0.f, 0.f, 0.f, 0.f};
  #pragma unroll
  for (int i = 0; i < 4; i++)
    #pragma unroll
    for (int j = 0; j < 2; j++) acc[i][j] = zero;

  for (int kb = 0; kb < NKB; kb++) {
    int khw = kb >> 1;
    int kh = khw / 3;
    int kw = khw - kh * 3;
    int dB = kh * XT_ROW + kw * 128 + ((kb & 1) << 6);
    int dA = kb * 64;
    __syncthreads();                      // prior frag reads complete
    load_lds16(wp + offA0 + dA, dA0);
    load_lds16(wp + offA1 + dA, dA1);
    load_lds16(xTb + offB0 + dB, dB0);
    load_lds16(xTb + offB1 + dB, dB1);
    __syncthreads();                      // DMA drained (vmcnt(0) at barrier)
    #pragma unroll
    for (int kk = 0; kk < 2; kk++) {
      bf16x8 af[4], bfr[2];
      int pc = ((kk * 4 + quad) ^ x7) << 3;
      #pragma unroll
      for (int i = 0; i < 4; i++)
        af[i] = *reinterpret_cast<const bf16x8*>(&As[(co_b + i * 16 + l15) * 64 + pc]);
      #pragma unroll
      for (int j = 0; j < 2; j++)
        bfr[j] = *reinterpret_cast<const bf16x8*>(&Bs[(s_base + j * 16 + l15) * 64 + pc]);
      #pragma unroll
      for (int i = 0; i < 4; i++)
        #pragma unroll
        for (int j = 0; j < 2; j++)
          acc[i][j] = __builtin_amdgcn_mfma_f32_16x16x32_bf16(af[i], bfr[j], acc[i][j], 0, 0, 0);
    }
  }

  // epilogue: D col (l15) -> s, row (quad*4+r) -> co
  float* ob = out + (size_t)b * COUT * SS + y0 * 56;
  #pragma unroll
  for (int i = 0; i < 4; i++) {
    #pragma unroll
    for (int j = 0; j < 2; j++) {
      int sl = s_base + j * 16 + l15;
      if (sl < 112) {
        int row = (sl >= 56) ? 1 : 0;
        int col = sl - row * 56;
        #pragma unroll
        for (int r = 0; r < 4; r++) {
          int co = co_b + i * 16 + quad * 4 + r;
          ob[(size_t)co * SS + row * 56 + col] = acc[i][j][r];
        }
      }
    }
  }
}

extern "C" void kernel_launch(void* const* d_in, const int* in_sizes, int n_in,
                              void* d_out, int out_size, void* d_ws, size_t ws_size,
                              hipStream_t stream) {
  const float* x      = (const float*)d_in[0];
  const float* w_mask = (const float*)d_in[1];
  const float* b_mask = (const float*)d_in[2];
  const float* w1     = (const float*)d_in[3];
  const float* b1     = (const float*)d_in[4];
  const float* ln_g   = (const float*)d_in[5];
  const float* ln_b   = (const float*)d_in[6];
  const float* w2     = (const float*)d_in[7];
  const float* b2     = (const float*)d_in[8];
  const float* w_fc   = (const float*)d_in[9];
  const float* b_fc   = (const float*)d_in[10];
  float* out = (float*)d_out;

  char* ws = (char*)d_ws;
  unsigned short* xT  = (unsigned short*)(ws);               // 15,204,352 B
  unsigned short* wdw = (unsigned short*)(ws + 15204352);    //  4,718,592 B
  float* rowsum = (float*)(ws + 19922944);                   //      3,712 B
  float* pctx   = (float*)(ws + 19927040);                   //    475,136 B
  // total ws use: ~20.4 MB

  k0_padT<<<dim3(58, 16),  dim3(256), 0, stream>>>(x, w_mask, b_mask, xT, rowsum, pctx);
  k5_gen <<<dim3(128, 16), dim3(128), 0, stream>>>(rowsum, pctx, w1, b1, ln_g, ln_b,
                                                   w2, b2, w_fc, b_fc, wdw);
  k6_conv<<<dim3(28, 16),  dim3(512), 0, stream>>>(xT, wdw, out);
}